// Round 13
// baseline (382.888 us; speedup 1.0000x reference)
//
#include <hip/hip_runtime.h>

#define FEAT 128
#define EMB 64
#define NB 256          // blocks for edge chunking (hist/scatter)

typedef unsigned short u16;

__device__ inline u16 f2bf(float f) {
    unsigned u = __float_as_uint(f);
    unsigned r = (u + 0x7FFFu + ((u >> 16) & 1u)) >> 16;
    return (u16)r;
}
__device__ inline unsigned pack2(float lo, float hi) {
    return ((unsigned)f2bf(hi) << 16) | (unsigned)f2bf(lo);
}
__device__ inline void acc8(float* acc, uint4 v) {
    acc[0] += __uint_as_float(v.x << 16);
    acc[1] += __uint_as_float(v.x & 0xFFFF0000u);
    acc[2] += __uint_as_float(v.y << 16);
    acc[3] += __uint_as_float(v.y & 0xFFFF0000u);
    acc[4] += __uint_as_float(v.z << 16);
    acc[5] += __uint_as_float(v.z & 0xFFFF0000u);
    acc[6] += __uint_as_float(v.w << 16);
    acc[7] += __uint_as_float(v.w & 0xFFFF0000u);
}

// ============ CSR build: 2-level counting sort, LDS atomics only ============

__global__ __launch_bounds__(256) void hist_kernel(const int* __restrict__ edge_dst,
        int* __restrict__ table, int n_edges, int nbuck, int chunk) {
    __shared__ int hist[256];
    int t = threadIdx.x, b = blockIdx.x;
    hist[t] = 0;
    __syncthreads();
    int start = b * chunk, end = min(start + chunk, n_edges);
    for (int e = start + t; e < end; e += 256) {
        int d = __builtin_nontemporal_load(&edge_dst[e]);
        atomicAdd(&hist[d >> 8], 1);
    }
    __syncthreads();
    if (t < nbuck) table[t * NB + b] = hist[t];
}

__global__ void block_sum_kernel(const int* __restrict__ v, int* __restrict__ bsum, int n) {
    __shared__ int sd[256];
    int t = threadIdx.x;
    int i = blockIdx.x * 256 + t;
    sd[t] = (i < n) ? v[i] : 0;
    __syncthreads();
    for (int off = 128; off > 0; off >>= 1) {
        if (t < off) sd[t] += sd[t + off];
        __syncthreads();
    }
    if (t == 0) bsum[blockIdx.x] = sd[0];
}

__global__ void scan_bsum_kernel(const int* __restrict__ bsum, int* __restrict__ boff, int nb) {
    __shared__ int sd[256];
    int t = threadIdx.x;
    int v = (t < nb) ? bsum[t] : 0;
    sd[t] = v;
    __syncthreads();
    for (int off = 1; off < 256; off <<= 1) {
        int u = (t >= off) ? sd[t - off] : 0;
        __syncthreads();
        sd[t] += u;
        __syncthreads();
    }
    if (t < nb) boff[t] = sd[t] - v;
}

__global__ void scan_table_kernel(const int* __restrict__ tin, const int* __restrict__ boff,
                                  int* __restrict__ tout, int n) {
    __shared__ int sd[256];
    int t = threadIdx.x;
    int i = blockIdx.x * 256 + t;
    int v = (i < n) ? tin[i] : 0;
    sd[t] = v;
    __syncthreads();
    for (int off = 1; off < 256; off <<= 1) {
        int u = (t >= off) ? sd[t - off] : 0;
        __syncthreads();
        sd[t] += u;
        __syncthreads();
    }
    if (i < n) tout[i] = boff[blockIdx.x] + sd[t] - v;
}

__global__ __launch_bounds__(256) void scatter_kernel(
        const int* __restrict__ edge_src, const int* __restrict__ edge_dst,
        const int* __restrict__ tscan, unsigned* __restrict__ pairs,
        int n_edges, int nbuck, int chunk) {
    __shared__ int cur[256];
    int t = threadIdx.x, b = blockIdx.x;
    if (t < nbuck) cur[t] = tscan[t * NB + b];
    __syncthreads();
    int start = b * chunk, end = min(start + chunk, n_edges);
    for (int e = start + t; e < end; e += 256) {
        int d = __builtin_nontemporal_load(&edge_dst[e]);
        int s = __builtin_nontemporal_load(&edge_src[e]);
        int pos = atomicAdd(&cur[d >> 8], 1);
        pairs[pos] = ((unsigned)(d & 255) << 16) | (unsigned)s;
    }
}

__global__ __launch_bounds__(256) void finalize_kernel(
        const unsigned* __restrict__ pairs, const int* __restrict__ boff,
        int* __restrict__ rowptr, float* __restrict__ dinv, u16* __restrict__ csr,
        int n_edges, int N, int nbuck) {
    __shared__ int hist[256];
    __shared__ int scan[256];
    __shared__ int cur[256];
    int b = blockIdx.x, t = threadIdx.x;
    int node0 = b << 8;
    int base = boff[b];
    int end  = (b + 1 < nbuck) ? boff[b + 1] : n_edges;
    hist[t] = 0;
    __syncthreads();
    for (int p = base + t; p < end; p += 256)
        atomicAdd(&hist[pairs[p] >> 16], 1);
    __syncthreads();
    int v = hist[t];
    scan[t] = v;
    __syncthreads();
    for (int off = 1; off < 256; off <<= 1) {
        int u = (t >= off) ? scan[t - off] : 0;
        __syncthreads();
        scan[t] += u;
        __syncthreads();
    }
    int excl = scan[t] - v;
    cur[t] = base + excl;
    int node = node0 + t;
    if (node < N) {
        rowptr[node] = base + excl;
        dinv[node] = rsqrtf(fmaxf((float)v, 1.0f));
    }
    if (b == 0 && t == 0) rowptr[N] = n_edges;
    __syncthreads();
    for (int p = base + t; p < end; p += 256) {
        unsigned pr = pairs[p];
        int pos = atomicAdd(&cur[pr >> 16], 1);
        csr[pos] = (u16)(pr & 0xFFFFu);
    }
}

// ============ MLP: A = relu(relu(feat@W1+b1)@W2+b2); Ay = bf16(A*dinv) ============
// LDS = 32KB only (feat tile, swizzled; sH overlays). Weights read from global
// (L1 broadcast; W1/W2 shared by all blocks -> hot in cache). 5 blocks/CU.

__global__ __launch_bounds__(256) void mlp_kernel(const float* __restrict__ feat,
        const float* __restrict__ W1, const float* __restrict__ b1,
        const float* __restrict__ W2, const float* __restrict__ b2,
        const float* __restrict__ dinv,
        float* __restrict__ A, u16* __restrict__ Ay, int n) {
    __shared__ float sBuf[64 * FEAT];   // 32KB
    int tid = threadIdx.x;
    int row0 = blockIdx.x * 64;

    for (int i = tid; i < 64 * FEAT; i += 256) {
        int r = i >> 7, c = i & 127;
        int gr = row0 + r;
        int s = c >> 2;
        int idx = r * FEAT + (((s ^ ((r >> 2) & 7)) << 2) | (c & 3));
        sBuf[idx] = (gr < n) ? feat[(size_t)gr * FEAT + c] : 0.0f;
    }
    __syncthreads();

    int tx = tid & 15, ty = tid >> 4;
    float4 b1v = *(const float4*)&b1[tx * 4];
    float acc[4][4];
    #pragma unroll
    for (int i = 0; i < 4; ++i) { acc[i][0]=b1v.x; acc[i][1]=b1v.y; acc[i][2]=b1v.z; acc[i][3]=b1v.w; }

    #pragma unroll 4
    for (int k4 = 0; k4 < FEAT / 4; ++k4) {
        float4 a4[4];
        #pragma unroll
        for (int i = 0; i < 4; ++i) {
            int r = ty * 4 + i;
            a4[i] = *(const float4*)&sBuf[r * FEAT + ((k4 ^ (ty & 7)) << 2)];
        }
        #pragma unroll
        for (int kk = 0; kk < 4; ++kk) {
            float4 bv = *(const float4*)&W1[(k4 * 4 + kk) * EMB + tx * 4];
            #pragma unroll
            for (int i = 0; i < 4; ++i) {
                float a = ((const float*)&a4[i])[kk];
                acc[i][0] = fmaf(a, bv.x, acc[i][0]);
                acc[i][1] = fmaf(a, bv.y, acc[i][1]);
                acc[i][2] = fmaf(a, bv.z, acc[i][2]);
                acc[i][3] = fmaf(a, bv.w, acc[i][3]);
            }
        }
    }
    __syncthreads();

    float* sH = sBuf;   // 16KB overlay
    #pragma unroll
    for (int i = 0; i < 4; ++i) {
        int r = ty * 4 + i;
        float4 hv;
        hv.x = fmaxf(acc[i][0], 0.0f); hv.y = fmaxf(acc[i][1], 0.0f);
        hv.z = fmaxf(acc[i][2], 0.0f); hv.w = fmaxf(acc[i][3], 0.0f);
        *(float4*)&sH[r * EMB + ((tx ^ (ty & 7)) << 2)] = hv;
    }
    __syncthreads();

    float4 b2v = *(const float4*)&b2[tx * 4];
    float acc2[4][4];
    #pragma unroll
    for (int i = 0; i < 4; ++i) { acc2[i][0]=b2v.x; acc2[i][1]=b2v.y; acc2[i][2]=b2v.z; acc2[i][3]=b2v.w; }

    #pragma unroll 4
    for (int k4 = 0; k4 < EMB / 4; ++k4) {
        float4 a4[4];
        #pragma unroll
        for (int i = 0; i < 4; ++i) {
            int r = ty * 4 + i;
            a4[i] = *(const float4*)&sH[r * EMB + ((k4 ^ (ty & 7)) << 2)];
        }
        #pragma unroll
        for (int kk = 0; kk < 4; ++kk) {
            float4 bv = *(const float4*)&W2[(k4 * 4 + kk) * EMB + tx * 4];
            #pragma unroll
            for (int i = 0; i < 4; ++i) {
                float a = ((const float*)&a4[i])[kk];
                acc2[i][0] = fmaf(a, bv.x, acc2[i][0]);
                acc2[i][1] = fmaf(a, bv.y, acc2[i][1]);
                acc2[i][2] = fmaf(a, bv.z, acc2[i][2]);
                acc2[i][3] = fmaf(a, bv.w, acc2[i][3]);
            }
        }
    }

    #pragma unroll
    for (int i = 0; i < 4; ++i) {
        int gr = row0 + ty * 4 + i;
        if (gr < n) {
            float di = dinv[gr];
            float4 o;
            o.x = fmaxf(acc2[i][0], 0.0f); o.y = fmaxf(acc2[i][1], 0.0f);
            o.z = fmaxf(acc2[i][2], 0.0f); o.w = fmaxf(acc2[i][3], 0.0f);
            *(float4*)&A[(size_t)gr * EMB + tx * 4] = o;
            uint2 oy;
            oy.x = pack2(o.x * di, o.y * di);
            oy.y = pack2(o.z * di, o.w * di);
            *(uint2*)&Ay[(size_t)gr * EMB + tx * 4] = oy;
        }
    }
}

// ============ Laplacian kernels ============
// y = bf16(x*dinv) packed 2/uint. 8 lanes/node, uint4 per lane.
// Edge loop unrolled x16 with dual accumulators (ILP probe).

__global__ __launch_bounds__(256) void lap_kernel(
        const float4* __restrict__ x, const uint4* __restrict__ y,
        float4* __restrict__ Bx, uint4* __restrict__ By,
        const int* __restrict__ rowptr, const u16* __restrict__ csr,
        const float* __restrict__ dinv, int n) {
    int tid = blockIdx.x * blockDim.x + threadIdx.x;
    int g = tid >> 3, gl = tid & 7;
    if (g >= n) return;
    int s = rowptr[g], e = rowptr[g + 1];
    float acc[8] = {0.f,0.f,0.f,0.f,0.f,0.f,0.f,0.f};
    float accB[8] = {0.f,0.f,0.f,0.f,0.f,0.f,0.f,0.f};
    int p = s;
    for (; p + 15 < e; p += 16) {
        int idx[16];
        #pragma unroll
        for (int k = 0; k < 16; ++k) idx[k] = csr[p + k];
        uint4 v[16];
        #pragma unroll
        for (int k = 0; k < 16; ++k) v[k] = y[(size_t)idx[k] * 8 + gl];
        #pragma unroll
        for (int k = 0; k < 16; k += 2) { acc8(acc, v[k]); acc8(accB, v[k + 1]); }
    }
    for (; p + 3 < e; p += 4) {
        int i0 = csr[p], i1 = csr[p+1], i2 = csr[p+2], i3 = csr[p+3];
        uint4 v0 = y[(size_t)i0 * 8 + gl];
        uint4 v1 = y[(size_t)i1 * 8 + gl];
        uint4 v2 = y[(size_t)i2 * 8 + gl];
        uint4 v3 = y[(size_t)i3 * 8 + gl];
        acc8(acc, v0); acc8(accB, v1); acc8(acc, v2); acc8(accB, v3);
    }
    for (; p < e; ++p) acc8(acc, y[(size_t)csr[p] * 8 + gl]);
    #pragma unroll
    for (int k = 0; k < 8; ++k) acc[k] += accB[k];
    float di = dinv[g];
    float4 xa = x[(size_t)g * 16 + gl * 2];
    float4 xb = x[(size_t)g * 16 + gl * 2 + 1];
    float4 oa, ob;
    oa.x = xa.x - acc[0] * di; oa.y = xa.y - acc[1] * di;
    oa.z = xa.z - acc[2] * di; oa.w = xa.w - acc[3] * di;
    ob.x = xb.x - acc[4] * di; ob.y = xb.y - acc[5] * di;
    ob.z = xb.z - acc[6] * di; ob.w = xb.w - acc[7] * di;
    Bx[(size_t)g * 16 + gl * 2] = oa;
    Bx[(size_t)g * 16 + gl * 2 + 1] = ob;
    uint4 oy;
    oy.x = pack2(oa.x * di, oa.y * di);
    oy.y = pack2(oa.z * di, oa.w * di);
    oy.z = pack2(ob.x * di, ob.y * di);
    oy.w = pack2(ob.z * di, ob.w * di);
    By[(size_t)g * 8 + gl] = oy;
}

__global__ __launch_bounds__(256) void theta_kernel(
        float4* __restrict__ Ax, uint4* __restrict__ Ay,
        const float4* __restrict__ Bx, const uint4* __restrict__ By,
        const int* __restrict__ rowptr, const u16* __restrict__ csr,
        const float* __restrict__ dinv, int n, float t0, float t1, float t2, int skip_a) {
    int tid = blockIdx.x * blockDim.x + threadIdx.x;
    int g = tid >> 3, gl = tid & 7;
    if (g >= n) return;
    int s = rowptr[g], e = rowptr[g + 1];
    float acc[8] = {0.f,0.f,0.f,0.f,0.f,0.f,0.f,0.f};
    float accB[8] = {0.f,0.f,0.f,0.f,0.f,0.f,0.f,0.f};
    int p = s;
    for (; p + 15 < e; p += 16) {
        int idx[16];
        #pragma unroll
        for (int k = 0; k < 16; ++k) idx[k] = csr[p + k];
        uint4 v[16];
        #pragma unroll
        for (int k = 0; k < 16; ++k) v[k] = By[(size_t)idx[k] * 8 + gl];
        #pragma unroll
        for (int k = 0; k < 16; k += 2) { acc8(acc, v[k]); acc8(accB, v[k + 1]); }
    }
    for (; p + 3 < e; p += 4) {
        int i0 = csr[p], i1 = csr[p+1], i2 = csr[p+2], i3 = csr[p+3];
        uint4 v0 = By[(size_t)i0 * 8 + gl];
        uint4 v1 = By[(size_t)i1 * 8 + gl];
        uint4 v2 = By[(size_t)i2 * 8 + gl];
        uint4 v3 = By[(size_t)i3 * 8 + gl];
        acc8(acc, v0); acc8(accB, v1); acc8(acc, v2); acc8(accB, v3);
    }
    for (; p < e; ++p) acc8(acc, By[(size_t)csr[p] * 8 + gl]);
    #pragma unroll
    for (int k = 0; k < 8; ++k) acc[k] += accB[k];
    float di = dinv[g];
    float4 ba = Bx[(size_t)g * 16 + gl * 2];
    float4 bb = Bx[(size_t)g * 16 + gl * 2 + 1];
    float4 aa = {0.f,0.f,0.f,0.f}, ab = {0.f,0.f,0.f,0.f};
    if (!skip_a) {
        aa = Ax[(size_t)g * 16 + gl * 2];
        ab = Ax[(size_t)g * 16 + gl * 2 + 1];
    }
    float4 oa, ob;
    oa.x = t0 * aa.x + t1 * ba.x + t2 * (ba.x - acc[0] * di);
    oa.y = t0 * aa.y + t1 * ba.y + t2 * (ba.y - acc[1] * di);
    oa.z = t0 * aa.z + t1 * ba.z + t2 * (ba.z - acc[2] * di);
    oa.w = t0 * aa.w + t1 * ba.w + t2 * (ba.w - acc[3] * di);
    ob.x = t0 * ab.x + t1 * bb.x + t2 * (bb.x - acc[4] * di);
    ob.y = t0 * ab.y + t1 * bb.y + t2 * (bb.y - acc[5] * di);
    ob.z = t0 * ab.z + t1 * bb.z + t2 * (bb.z - acc[6] * di);
    ob.w = t0 * ab.w + t1 * bb.w + t2 * (bb.w - acc[7] * di);
    Ax[(size_t)g * 16 + gl * 2] = oa;
    Ax[(size_t)g * 16 + gl * 2 + 1] = ob;
    uint4 oy;
    oy.x = pack2(oa.x * di, oa.y * di);
    oy.y = pack2(oa.z * di, oa.w * di);
    oy.z = pack2(ob.x * di, ob.y * di);
    oy.w = pack2(ob.z * di, ob.w * di);
    Ay[(size_t)g * 8 + gl] = oy;
}

__global__ __launch_bounds__(256) void theta_sel_kernel(
        const float4* __restrict__ Bx, const uint4* __restrict__ By,
        const int* __restrict__ rowptr, const u16* __restrict__ csr,
        const float* __restrict__ dinv, const int* __restrict__ nodes,
        float4* __restrict__ hsel, int n, float t2) {
    int tid = blockIdx.x * blockDim.x + threadIdx.x;
    int i = tid >> 3, gl = tid & 7;
    if (i >= n) return;
    int g = nodes[i];
    int s = rowptr[g], e = rowptr[g + 1];
    float acc[8] = {0.f,0.f,0.f,0.f,0.f,0.f,0.f,0.f};
    int p = s;
    for (; p + 7 < e; p += 8) {
        int i0 = csr[p],   i1 = csr[p+1], i2 = csr[p+2], i3 = csr[p+3];
        int i4 = csr[p+4], i5 = csr[p+5], i6 = csr[p+6], i7 = csr[p+7];
        uint4 v0 = By[(size_t)i0 * 8 + gl];
        uint4 v1 = By[(size_t)i1 * 8 + gl];
        uint4 v2 = By[(size_t)i2 * 8 + gl];
        uint4 v3 = By[(size_t)i3 * 8 + gl];
        uint4 v4 = By[(size_t)i4 * 8 + gl];
        uint4 v5 = By[(size_t)i5 * 8 + gl];
        uint4 v6 = By[(size_t)i6 * 8 + gl];
        uint4 v7 = By[(size_t)i7 * 8 + gl];
        acc8(acc, v0); acc8(acc, v1); acc8(acc, v2); acc8(acc, v3);
        acc8(acc, v4); acc8(acc, v5); acc8(acc, v6); acc8(acc, v7);
    }
    for (; p < e; ++p) acc8(acc, By[(size_t)csr[p] * 8 + gl]);
    float di = dinv[g];
    float4 ba = Bx[(size_t)g * 16 + gl * 2];
    float4 bb = Bx[(size_t)g * 16 + gl * 2 + 1];
    float4 oa, ob;
    oa.x = t2 * (ba.x - acc[0] * di); oa.y = t2 * (ba.y - acc[1] * di);
    oa.z = t2 * (ba.z - acc[2] * di); oa.w = t2 * (ba.w - acc[3] * di);
    ob.x = t2 * (bb.x - acc[4] * di); ob.y = t2 * (bb.y - acc[5] * di);
    ob.z = t2 * (bb.z - acc[6] * di); ob.w = t2 * (bb.w - acc[7] * di);
    hsel[(size_t)i * 16 + gl * 2] = oa;
    hsel[(size_t)i * 16 + gl * 2 + 1] = ob;
}

// ============ Final stage 1: vtmp = feat[node] + hsel[i]@W3 + b3 ; scores ============
// W3 read from global (L1 broadcast), LDS = sHt only.

__global__ __launch_bounds__(256) void final1_kernel(const float* __restrict__ feat,
        const float* __restrict__ hsel, const float* __restrict__ W3, const float* __restrict__ b3,
        const float* __restrict__ Wclf, const float* __restrict__ bclf,
        const int* __restrict__ nodes, float* __restrict__ vtmp, float* __restrict__ scores,
        int n) {
    __shared__ float sHt[64 * 68];       // 17KB padded
    __shared__ float sWclf[FEAT * 2];
    __shared__ float sbclf[2];
    __shared__ int sNodes[64];
    int tid = threadIdx.x;
    int base = blockIdx.x * 64;

    for (int i = tid; i < FEAT * 2; i += 256) sWclf[i] = Wclf[i];
    if (tid < 2) sbclf[tid] = bclf[tid];
    if (tid < 64) {
        int gi = base + tid;
        sNodes[tid] = (gi < n) ? nodes[gi] : 0;
    }
    __syncthreads();
    for (int it = 0; it < 16; ++it) {
        int id = it * 256 + tid;
        int r = id >> 6, c = id & 63;
        int gi = base + r;
        sHt[r * 68 + c] = (gi < n) ? hsel[(size_t)gi * EMB + c] : 0.0f;
    }
    __syncthreads();

    {
        int wv = tid >> 6, ln = tid & 63;
        float bc0 = sbclf[0], bc1 = sbclf[1];
        for (int q = 0; q < 16; ++q) {
            int r = wv * 16 + q;
            int nd = sNodes[r];
            float f0 = feat[(size_t)nd * FEAT + ln];
            float f1 = feat[(size_t)nd * FEAT + 64 + ln];
            float p0 = f0 * sWclf[ln * 2]     + f1 * sWclf[(64 + ln) * 2];
            float p1 = f0 * sWclf[ln * 2 + 1] + f1 * sWclf[(64 + ln) * 2 + 1];
            #pragma unroll
            for (int off = 32; off > 0; off >>= 1) {
                p0 += __shfl_xor(p0, off);
                p1 += __shfl_xor(p1, off);
            }
            int gi = base + r;
            if (ln == 0 && gi < n) {
                scores[(size_t)gi * 2]     = p0 + bc0;
                scores[(size_t)gi * 2 + 1] = p1 + bc1;
            }
        }
    }

    int tx = tid & 31, ty = tid >> 5;
    float acc[8][4];
    #pragma unroll
    for (int i = 0; i < 8; ++i)
        #pragma unroll
        for (int j = 0; j < 4; ++j) acc[i][j] = 0.0f;

    #pragma unroll 2
    for (int k4 = 0; k4 < EMB / 4; ++k4) {
        float4 a4[8];
        #pragma unroll
        for (int i = 0; i < 8; ++i)
            a4[i] = *(const float4*)&sHt[(ty * 8 + i) * 68 + k4 * 4];
        #pragma unroll
        for (int kk = 0; kk < 4; ++kk) {
            float4 bv = *(const float4*)&W3[(k4 * 4 + kk) * FEAT + tx * 4];
            #pragma unroll
            for (int i = 0; i < 8; ++i) {
                float a = ((const float*)&a4[i])[kk];
                acc[i][0] = fmaf(a, bv.x, acc[i][0]);
                acc[i][1] = fmaf(a, bv.y, acc[i][1]);
                acc[i][2] = fmaf(a, bv.z, acc[i][2]);
                acc[i][3] = fmaf(a, bv.w, acc[i][3]);
            }
        }
    }

    float4 b3v = *(const float4*)&b3[tx * 4];
    #pragma unroll
    for (int i = 0; i < 8; ++i) {
        int r = ty * 8 + i;
        int gi = base + r;
        int nd = sNodes[r];
        float4 fv = *(const float4*)&feat[(size_t)nd * FEAT + tx * 4];
        float4 o;
        o.x = acc[i][0] + b3v.x + fv.x;
        o.y = acc[i][1] + b3v.y + fv.y;
        o.z = acc[i][2] + b3v.z + fv.z;
        o.w = acc[i][3] + b3v.w + fv.w;
        if (gi < n) *(float4*)&vtmp[(size_t)gi * FEAT + tx * 4] = o;
    }
}

// ============ Final stage 2: out = relu(vtmp @ weight) ============
// weight read from global; LDS = sV only (32KB, swizzled).

__global__ __launch_bounds__(256) void final2_kernel(const float* __restrict__ vtmp,
        const float* __restrict__ weight, float* __restrict__ outc, int n) {
    __shared__ float sV[64 * FEAT];     // 32KB
    int tid = threadIdx.x;
    int base = blockIdx.x * 64;
    for (int i = tid; i < 64 * FEAT; i += 256) {
        int r = i >> 7, c = i & 127;
        int gi = base + r;
        int s = c >> 2;
        int idx = r * FEAT + (((s ^ ((r >> 2) & 7)) << 2) | (c & 3));
        sV[idx] = (gi < n) ? vtmp[(size_t)gi * FEAT + c] : 0.0f;
    }
    __syncthreads();

    int tx = tid & 15, ty = tid >> 4;
    float acc[4][4];
    #pragma unroll
    for (int i = 0; i < 4; ++i)
        #pragma unroll
        for (int j = 0; j < 4; ++j) acc[i][j] = 0.0f;

    #pragma unroll 4
    for (int k4 = 0; k4 < FEAT / 4; ++k4) {
        float4 a4[4];
        #pragma unroll
        for (int i = 0; i < 4; ++i) {
            int r = ty * 4 + i;
            a4[i] = *(const float4*)&sV[r * FEAT + ((k4 ^ (ty & 7)) << 2)];
        }
        #pragma unroll
        for (int kk = 0; kk < 4; ++kk) {
            float4 bv = *(const float4*)&weight[(k4 * 4 + kk) * EMB + tx * 4];
            #pragma unroll
            for (int i = 0; i < 4; ++i) {
                float a = ((const float*)&a4[i])[kk];
                acc[i][0] = fmaf(a, bv.x, acc[i][0]);
                acc[i][1] = fmaf(a, bv.y, acc[i][1]);
                acc[i][2] = fmaf(a, bv.z, acc[i][2]);
                acc[i][3] = fmaf(a, bv.w, acc[i][3]);
            }
        }
    }

    #pragma unroll
    for (int i = 0; i < 4; ++i) {
        int gi = base + ty * 4 + i;
        if (gi < n) {
            float4 o;
            o.x = fmaxf(acc[i][0], 0.0f); o.y = fmaxf(acc[i][1], 0.0f);
            o.z = fmaxf(acc[i][2], 0.0f); o.w = fmaxf(acc[i][3], 0.0f);
            *(float4*)&outc[(size_t)gi * EMB + tx * 4] = o;
        }
    }
}

// ============ launch ============

extern "C" void kernel_launch(void* const* d_in, const int* in_sizes, int n_in,
                              void* d_out, int out_size, void* d_ws, size_t ws_size,
                              hipStream_t stream) {
    const float* feat   = (const float*)d_in[0];
    const float* Wclf   = (const float*)d_in[1];
    const float* bclf   = (const float*)d_in[2];
    const float* W1     = (const float*)d_in[3];
    const float* b1     = (const float*)d_in[4];
    const float* W2     = (const float*)d_in[5];
    const float* b2     = (const float*)d_in[6];
    const float* W3     = (const float*)d_in[7];
    const float* b3     = (const float*)d_in[8];
    const float* weight = (const float*)d_in[9];
    const int* nodes    = (const int*)d_in[10];
    // d_in[11] = r1_neighs: DEAD (AGG_WEIGHT[0] == 0.0)
    const int* edge_src = (const int*)d_in[12];
    const int* edge_dst = (const int*)d_in[13];

    int n       = in_sizes[10];        // 8192
    int n_edges = in_sizes[12];        // 1600000
    int N       = in_sizes[0] / FEAT;  // 50000 (< 65536, required for u16 CSR)
    int nbuck   = (N + 255) >> 8;      // 196 (must be <= 256)
    int chunk   = (n_edges + NB - 1) / NB;

    char* ws = (char*)d_ws;
    size_t off = 0;
    auto alloc = [&](size_t bytes) -> void* {
        void* p = ws + off;
        off = (off + bytes + 255) & ~(size_t)255;
        return p;
    };
    int*      table  = (int*)     alloc((size_t)nbuck * NB * 4);
    int*      tscan  = (int*)     alloc((size_t)nbuck * NB * 4);
    int*      bsum   = (int*)     alloc(256 * 4);
    int*      boff   = (int*)     alloc(256 * 4);
    int*      rowptr = (int*)     alloc((size_t)(N + 1) * 4);
    float*    dinv   = (float*)   alloc((size_t)N * 4);
    unsigned* pairs  = (unsigned*)alloc((size_t)n_edges * 4);
    u16*      csr    = (u16*)     alloc((size_t)n_edges * 2);
    float*    Axf    = (float*)   alloc((size_t)N * EMB * 4);
    u16*      Ayf    = (u16*)     alloc((size_t)N * EMB * 2);
    float*    Bxf    = (float*)   alloc((size_t)N * EMB * 4);
    u16*      Byf    = (u16*)     alloc((size_t)N * EMB * 2);
    float*    hsel   = (float*)   alloc((size_t)n * EMB * 4);
    float*    vtmp   = (float*)   alloc((size_t)n * FEAT * 4);

    float* out_combined = (float*)d_out;                       // [n, 64]
    float* out_scores   = out_combined + (size_t)n * EMB;      // [n, 2]

    int L = nbuck * NB;   // 50176 table entries
    hist_kernel<<<NB, 256, 0, stream>>>(edge_dst, table, n_edges, nbuck, chunk);
    block_sum_kernel<<<nbuck, 256, 0, stream>>>(table, bsum, L);
    scan_bsum_kernel<<<1, 256, 0, stream>>>(bsum, boff, nbuck);
    scan_table_kernel<<<nbuck, 256, 0, stream>>>(table, boff, tscan, L);
    scatter_kernel<<<NB, 256, 0, stream>>>(edge_src, edge_dst, tscan, pairs, n_edges, nbuck, chunk);
    finalize_kernel<<<nbuck, 256, 0, stream>>>(pairs, boff, rowptr, dinv, csr, n_edges, N, nbuck);

    int mb = (N + 63) / 64;
    mlp_kernel<<<mb, 256, 0, stream>>>(feat, W1, b1, W2, b2, dinv, Axf, Ayf, N);

    int lb = ((size_t)N * 8 + 255) / 256;
    // conv 0: theta = (3, -3, 0.75)
    lap_kernel<<<lb, 256, 0, stream>>>((const float4*)Axf, (const uint4*)Ayf,
                                       (float4*)Bxf, (uint4*)Byf, rowptr, csr, dinv, N);
    theta_kernel<<<lb, 256, 0, stream>>>((float4*)Axf, (uint4*)Ayf,
                                         (const float4*)Bxf, (const uint4*)Byf,
                                         rowptr, csr, dinv, N, 3.f, -3.f, 0.75f, 0);
    // conv 1: theta = (0, 3, -1.5)
    lap_kernel<<<lb, 256, 0, stream>>>((const float4*)Axf, (const uint4*)Ayf,
                                       (float4*)Bxf, (uint4*)Byf, rowptr, csr, dinv, N);
    theta_kernel<<<lb, 256, 0, stream>>>((float4*)Axf, (uint4*)Ayf,
                                         (const float4*)Bxf, (const uint4*)Byf,
                                         rowptr, csr, dinv, N, 0.f, 3.f, -1.5f, 1);
    // conv 2: theta = (0, 0, 0.75) -> only needed at `nodes`
    lap_kernel<<<lb, 256, 0, stream>>>((const float4*)Axf, (const uint4*)Ayf,
                                       (float4*)Bxf, (uint4*)Byf, rowptr, csr, dinv, N);
    int selb = ((size_t)n * 8 + 255) / 256;
    theta_sel_kernel<<<selb, 256, 0, stream>>>((const float4*)Bxf, (const uint4*)Byf,
                                               rowptr, csr, dinv, nodes,
                                               (float4*)hsel, n, 0.75f);

    int fb = (n + 63) / 64;
    final1_kernel<<<fb, 256, 0, stream>>>(feat, hsel, W3, b3, Wclf, bclf, nodes,
                                          vtmp, out_scores, n);
    final2_kernel<<<fb, 256, 0, stream>>>(vtmp, weight, out_combined, n);
}

// Round 14
// 377.152 us; speedup vs baseline: 1.0152x; 1.0152x over previous
//
#include <hip/hip_runtime.h>

#define FEAT 128
#define EMB 64
#define NB 256          // blocks for edge chunking (hist/scatter)

typedef unsigned short u16;

__device__ inline u16 f2bf(float f) {
    unsigned u = __float_as_uint(f);
    unsigned r = (u + 0x7FFFu + ((u >> 16) & 1u)) >> 16;
    return (u16)r;
}
__device__ inline unsigned pack2(float lo, float hi) {
    return ((unsigned)f2bf(hi) << 16) | (unsigned)f2bf(lo);
}
__device__ inline void acc8(float* acc, uint4 v) {
    acc[0] += __uint_as_float(v.x << 16);
    acc[1] += __uint_as_float(v.x & 0xFFFF0000u);
    acc[2] += __uint_as_float(v.y << 16);
    acc[3] += __uint_as_float(v.y & 0xFFFF0000u);
    acc[4] += __uint_as_float(v.z << 16);
    acc[5] += __uint_as_float(v.z & 0xFFFF0000u);
    acc[6] += __uint_as_float(v.w << 16);
    acc[7] += __uint_as_float(v.w & 0xFFFF0000u);
}

// ============ CSR build: 2-level counting sort, LDS atomics only ============

__global__ __launch_bounds__(256) void hist_kernel(const int* __restrict__ edge_dst,
        int* __restrict__ table, int n_edges, int nbuck, int chunk) {
    __shared__ int hist[256];
    int t = threadIdx.x, b = blockIdx.x;
    hist[t] = 0;
    __syncthreads();
    int start = b * chunk, end = min(start + chunk, n_edges);
    for (int e = start + t; e < end; e += 256) {
        int d = __builtin_nontemporal_load(&edge_dst[e]);
        atomicAdd(&hist[d >> 8], 1);
    }
    __syncthreads();
    if (t < nbuck) table[t * NB + b] = hist[t];
}

__global__ void block_sum_kernel(const int* __restrict__ v, int* __restrict__ bsum, int n) {
    __shared__ int sd[256];
    int t = threadIdx.x;
    int i = blockIdx.x * 256 + t;
    sd[t] = (i < n) ? v[i] : 0;
    __syncthreads();
    for (int off = 128; off > 0; off >>= 1) {
        if (t < off) sd[t] += sd[t + off];
        __syncthreads();
    }
    if (t == 0) bsum[blockIdx.x] = sd[0];
}

__global__ void scan_bsum_kernel(const int* __restrict__ bsum, int* __restrict__ boff, int nb) {
    __shared__ int sd[256];
    int t = threadIdx.x;
    int v = (t < nb) ? bsum[t] : 0;
    sd[t] = v;
    __syncthreads();
    for (int off = 1; off < 256; off <<= 1) {
        int u = (t >= off) ? sd[t - off] : 0;
        __syncthreads();
        sd[t] += u;
        __syncthreads();
    }
    if (t < nb) boff[t] = sd[t] - v;
}

__global__ void scan_table_kernel(const int* __restrict__ tin, const int* __restrict__ boff,
                                  int* __restrict__ tout, int n) {
    __shared__ int sd[256];
    int t = threadIdx.x;
    int i = blockIdx.x * 256 + t;
    int v = (i < n) ? tin[i] : 0;
    sd[t] = v;
    __syncthreads();
    for (int off = 1; off < 256; off <<= 1) {
        int u = (t >= off) ? sd[t - off] : 0;
        __syncthreads();
        sd[t] += u;
        __syncthreads();
    }
    if (i < n) tout[i] = boff[blockIdx.x] + sd[t] - v;
}

__global__ __launch_bounds__(256) void scatter_kernel(
        const int* __restrict__ edge_src, const int* __restrict__ edge_dst,
        const int* __restrict__ tscan, unsigned* __restrict__ pairs,
        int n_edges, int nbuck, int chunk) {
    __shared__ int cur[256];
    int t = threadIdx.x, b = blockIdx.x;
    if (t < nbuck) cur[t] = tscan[t * NB + b];
    __syncthreads();
    int start = b * chunk, end = min(start + chunk, n_edges);
    for (int e = start + t; e < end; e += 256) {
        int d = __builtin_nontemporal_load(&edge_dst[e]);
        int s = __builtin_nontemporal_load(&edge_src[e]);
        int pos = atomicAdd(&cur[d >> 8], 1);
        pairs[pos] = ((unsigned)(d & 255) << 16) | (unsigned)s;
    }
}

__global__ __launch_bounds__(256) void finalize_kernel(
        const unsigned* __restrict__ pairs, const int* __restrict__ boff,
        int* __restrict__ rowptr, float* __restrict__ dinv, u16* __restrict__ csr,
        int n_edges, int N, int nbuck) {
    __shared__ int hist[256];
    __shared__ int scan[256];
    __shared__ int cur[256];
    int b = blockIdx.x, t = threadIdx.x;
    int node0 = b << 8;
    int base = boff[b];
    int end  = (b + 1 < nbuck) ? boff[b + 1] : n_edges;
    hist[t] = 0;
    __syncthreads();
    for (int p = base + t; p < end; p += 256)
        atomicAdd(&hist[pairs[p] >> 16], 1);
    __syncthreads();
    int v = hist[t];
    scan[t] = v;
    __syncthreads();
    for (int off = 1; off < 256; off <<= 1) {
        int u = (t >= off) ? scan[t - off] : 0;
        __syncthreads();
        scan[t] += u;
        __syncthreads();
    }
    int excl = scan[t] - v;
    cur[t] = base + excl;
    int node = node0 + t;
    if (node < N) {
        rowptr[node] = base + excl;
        dinv[node] = rsqrtf(fmaxf((float)v, 1.0f));
    }
    if (b == 0 && t == 0) rowptr[N] = n_edges;
    __syncthreads();
    for (int p = base + t; p < end; p += 256) {
        unsigned pr = pairs[p];
        int pos = atomicAdd(&cur[pr >> 16], 1);
        csr[pos] = (u16)(pr & 0xFFFFu);
    }
}

// ============ MLP: A = relu(relu(feat@W1+b1)@W2+b2); Ay = bf16(A*dinv) ============
// 32 rows/block (1563 blocks, ~6/CU), LDS 16KB, weights via global/L1 broadcast.

__global__ __launch_bounds__(256) void mlp_kernel(const float* __restrict__ feat,
        const float* __restrict__ W1, const float* __restrict__ b1,
        const float* __restrict__ W2, const float* __restrict__ b2,
        const float* __restrict__ dinv,
        float* __restrict__ A, u16* __restrict__ Ay, int n) {
    __shared__ float sBuf[32 * FEAT];   // 16KB
    int tid = threadIdx.x;
    int row0 = blockIdx.x * 32;

    for (int i = tid; i < 32 * FEAT; i += 256) {
        int r = i >> 7, c = i & 127;
        int gr = row0 + r;
        int s = c >> 2;
        int idx = r * FEAT + (((s ^ ((r >> 1) & 7)) << 2) | (c & 3));
        sBuf[idx] = (gr < n) ? feat[(size_t)gr * FEAT + c] : 0.0f;
    }
    __syncthreads();

    int tx = tid & 15, ty = tid >> 4;   // 16 col-groups x 16 row-groups (2 rows each)
    float4 b1v = *(const float4*)&b1[tx * 4];
    float acc[2][4];
    #pragma unroll
    for (int i = 0; i < 2; ++i) { acc[i][0]=b1v.x; acc[i][1]=b1v.y; acc[i][2]=b1v.z; acc[i][3]=b1v.w; }

    #pragma unroll 4
    for (int k4 = 0; k4 < FEAT / 4; ++k4) {
        float4 a4[2];
        #pragma unroll
        for (int i = 0; i < 2; ++i) {
            int r = ty * 2 + i;
            a4[i] = *(const float4*)&sBuf[r * FEAT + ((k4 ^ (ty & 7)) << 2)];
        }
        #pragma unroll
        for (int kk = 0; kk < 4; ++kk) {
            float4 bv = *(const float4*)&W1[(k4 * 4 + kk) * EMB + tx * 4];
            #pragma unroll
            for (int i = 0; i < 2; ++i) {
                float a = ((const float*)&a4[i])[kk];
                acc[i][0] = fmaf(a, bv.x, acc[i][0]);
                acc[i][1] = fmaf(a, bv.y, acc[i][1]);
                acc[i][2] = fmaf(a, bv.z, acc[i][2]);
                acc[i][3] = fmaf(a, bv.w, acc[i][3]);
            }
        }
    }
    __syncthreads();

    float* sH = sBuf;   // 8KB overlay: [32][64]
    #pragma unroll
    for (int i = 0; i < 2; ++i) {
        int r = ty * 2 + i;
        float4 hv;
        hv.x = fmaxf(acc[i][0], 0.0f); hv.y = fmaxf(acc[i][1], 0.0f);
        hv.z = fmaxf(acc[i][2], 0.0f); hv.w = fmaxf(acc[i][3], 0.0f);
        *(float4*)&sH[r * EMB + ((tx ^ (ty & 7)) << 2)] = hv;
    }
    __syncthreads();

    float4 b2v = *(const float4*)&b2[tx * 4];
    float acc2[2][4];
    #pragma unroll
    for (int i = 0; i < 2; ++i) { acc2[i][0]=b2v.x; acc2[i][1]=b2v.y; acc2[i][2]=b2v.z; acc2[i][3]=b2v.w; }

    #pragma unroll 4
    for (int k4 = 0; k4 < EMB / 4; ++k4) {
        float4 a4[2];
        #pragma unroll
        for (int i = 0; i < 2; ++i) {
            int r = ty * 2 + i;
            a4[i] = *(const float4*)&sH[r * EMB + ((k4 ^ (ty & 7)) << 2)];
        }
        #pragma unroll
        for (int kk = 0; kk < 4; ++kk) {
            float4 bv = *(const float4*)&W2[(k4 * 4 + kk) * EMB + tx * 4];
            #pragma unroll
            for (int i = 0; i < 2; ++i) {
                float a = ((const float*)&a4[i])[kk];
                acc2[i][0] = fmaf(a, bv.x, acc2[i][0]);
                acc2[i][1] = fmaf(a, bv.y, acc2[i][1]);
                acc2[i][2] = fmaf(a, bv.z, acc2[i][2]);
                acc2[i][3] = fmaf(a, bv.w, acc2[i][3]);
            }
        }
    }

    #pragma unroll
    for (int i = 0; i < 2; ++i) {
        int gr = row0 + ty * 2 + i;
        if (gr < n) {
            float di = dinv[gr];
            float4 o;
            o.x = fmaxf(acc2[i][0], 0.0f); o.y = fmaxf(acc2[i][1], 0.0f);
            o.z = fmaxf(acc2[i][2], 0.0f); o.w = fmaxf(acc2[i][3], 0.0f);
            *(float4*)&A[(size_t)gr * EMB + tx * 4] = o;
            uint2 oy;
            oy.x = pack2(o.x * di, o.y * di);
            oy.y = pack2(o.z * di, o.w * di);
            *(uint2*)&Ay[(size_t)gr * EMB + tx * 4] = oy;
        }
    }
}

// ============ Laplacian kernels ============
// y = bf16(x*dinv) packed 2/uint. 8 lanes/node, uint4 per lane.
// Edge loop unrolled x8 (R10 sweet spot: ILP vs VGPR-occupancy).

__global__ __launch_bounds__(256) void lap_kernel(
        const float4* __restrict__ x, const uint4* __restrict__ y,
        float4* __restrict__ Bx, uint4* __restrict__ By,
        const int* __restrict__ rowptr, const u16* __restrict__ csr,
        const float* __restrict__ dinv, int n) {
    int tid = blockIdx.x * blockDim.x + threadIdx.x;
    int g = tid >> 3, gl = tid & 7;
    if (g >= n) return;
    int s = rowptr[g], e = rowptr[g + 1];
    float acc[8] = {0.f,0.f,0.f,0.f,0.f,0.f,0.f,0.f};
    int p = s;
    for (; p + 7 < e; p += 8) {
        int i0 = csr[p],   i1 = csr[p+1], i2 = csr[p+2], i3 = csr[p+3];
        int i4 = csr[p+4], i5 = csr[p+5], i6 = csr[p+6], i7 = csr[p+7];
        uint4 v0 = y[(size_t)i0 * 8 + gl];
        uint4 v1 = y[(size_t)i1 * 8 + gl];
        uint4 v2 = y[(size_t)i2 * 8 + gl];
        uint4 v3 = y[(size_t)i3 * 8 + gl];
        uint4 v4 = y[(size_t)i4 * 8 + gl];
        uint4 v5 = y[(size_t)i5 * 8 + gl];
        uint4 v6 = y[(size_t)i6 * 8 + gl];
        uint4 v7 = y[(size_t)i7 * 8 + gl];
        acc8(acc, v0); acc8(acc, v1); acc8(acc, v2); acc8(acc, v3);
        acc8(acc, v4); acc8(acc, v5); acc8(acc, v6); acc8(acc, v7);
    }
    for (; p < e; ++p) {
        int i0 = csr[p];
        acc8(acc, y[(size_t)i0 * 8 + gl]);
    }
    float di = dinv[g];
    float4 xa = x[(size_t)g * 16 + gl * 2];
    float4 xb = x[(size_t)g * 16 + gl * 2 + 1];
    float4 oa, ob;
    oa.x = xa.x - acc[0] * di; oa.y = xa.y - acc[1] * di;
    oa.z = xa.z - acc[2] * di; oa.w = xa.w - acc[3] * di;
    ob.x = xb.x - acc[4] * di; ob.y = xb.y - acc[5] * di;
    ob.z = xb.z - acc[6] * di; ob.w = xb.w - acc[7] * di;
    Bx[(size_t)g * 16 + gl * 2] = oa;
    Bx[(size_t)g * 16 + gl * 2 + 1] = ob;
    uint4 oy;
    oy.x = pack2(oa.x * di, oa.y * di);
    oy.y = pack2(oa.z * di, oa.w * di);
    oy.z = pack2(ob.x * di, ob.y * di);
    oy.w = pack2(ob.z * di, ob.w * di);
    By[(size_t)g * 8 + gl] = oy;
}

__global__ __launch_bounds__(256) void theta_kernel(
        float4* __restrict__ Ax, uint4* __restrict__ Ay,
        const float4* __restrict__ Bx, const uint4* __restrict__ By,
        const int* __restrict__ rowptr, const u16* __restrict__ csr,
        const float* __restrict__ dinv, int n, float t0, float t1, float t2, int skip_a) {
    int tid = blockIdx.x * blockDim.x + threadIdx.x;
    int g = tid >> 3, gl = tid & 7;
    if (g >= n) return;
    int s = rowptr[g], e = rowptr[g + 1];
    float acc[8] = {0.f,0.f,0.f,0.f,0.f,0.f,0.f,0.f};
    int p = s;
    for (; p + 7 < e; p += 8) {
        int i0 = csr[p],   i1 = csr[p+1], i2 = csr[p+2], i3 = csr[p+3];
        int i4 = csr[p+4], i5 = csr[p+5], i6 = csr[p+6], i7 = csr[p+7];
        uint4 v0 = By[(size_t)i0 * 8 + gl];
        uint4 v1 = By[(size_t)i1 * 8 + gl];
        uint4 v2 = By[(size_t)i2 * 8 + gl];
        uint4 v3 = By[(size_t)i3 * 8 + gl];
        uint4 v4 = By[(size_t)i4 * 8 + gl];
        uint4 v5 = By[(size_t)i5 * 8 + gl];
        uint4 v6 = By[(size_t)i6 * 8 + gl];
        uint4 v7 = By[(size_t)i7 * 8 + gl];
        acc8(acc, v0); acc8(acc, v1); acc8(acc, v2); acc8(acc, v3);
        acc8(acc, v4); acc8(acc, v5); acc8(acc, v6); acc8(acc, v7);
    }
    for (; p < e; ++p) {
        int i0 = csr[p];
        acc8(acc, By[(size_t)i0 * 8 + gl]);
    }
    float di = dinv[g];
    float4 ba = Bx[(size_t)g * 16 + gl * 2];
    float4 bb = Bx[(size_t)g * 16 + gl * 2 + 1];
    float4 aa = {0.f,0.f,0.f,0.f}, ab = {0.f,0.f,0.f,0.f};
    if (!skip_a) {
        aa = Ax[(size_t)g * 16 + gl * 2];
        ab = Ax[(size_t)g * 16 + gl * 2 + 1];
    }
    float4 oa, ob;
    oa.x = t0 * aa.x + t1 * ba.x + t2 * (ba.x - acc[0] * di);
    oa.y = t0 * aa.y + t1 * ba.y + t2 * (ba.y - acc[1] * di);
    oa.z = t0 * aa.z + t1 * ba.z + t2 * (ba.z - acc[2] * di);
    oa.w = t0 * aa.w + t1 * ba.w + t2 * (ba.w - acc[3] * di);
    ob.x = t0 * ab.x + t1 * bb.x + t2 * (bb.x - acc[4] * di);
    ob.y = t0 * ab.y + t1 * bb.y + t2 * (bb.y - acc[5] * di);
    ob.z = t0 * ab.z + t1 * bb.z + t2 * (bb.z - acc[6] * di);
    ob.w = t0 * ab.w + t1 * bb.w + t2 * (bb.w - acc[7] * di);
    Ax[(size_t)g * 16 + gl * 2] = oa;
    Ax[(size_t)g * 16 + gl * 2 + 1] = ob;
    uint4 oy;
    oy.x = pack2(oa.x * di, oa.y * di);
    oy.y = pack2(oa.z * di, oa.w * di);
    oy.z = pack2(ob.x * di, ob.y * di);
    oy.w = pack2(ob.z * di, ob.w * di);
    Ay[(size_t)g * 8 + gl] = oy;
}

__global__ __launch_bounds__(256) void theta_sel_kernel(
        const float4* __restrict__ Bx, const uint4* __restrict__ By,
        const int* __restrict__ rowptr, const u16* __restrict__ csr,
        const float* __restrict__ dinv, const int* __restrict__ nodes,
        float4* __restrict__ hsel, int n, float t2) {
    int tid = blockIdx.x * blockDim.x + threadIdx.x;
    int i = tid >> 3, gl = tid & 7;
    if (i >= n) return;
    int g = nodes[i];
    int s = rowptr[g], e = rowptr[g + 1];
    float acc[8] = {0.f,0.f,0.f,0.f,0.f,0.f,0.f,0.f};
    int p = s;
    for (; p + 7 < e; p += 8) {
        int i0 = csr[p],   i1 = csr[p+1], i2 = csr[p+2], i3 = csr[p+3];
        int i4 = csr[p+4], i5 = csr[p+5], i6 = csr[p+6], i7 = csr[p+7];
        uint4 v0 = By[(size_t)i0 * 8 + gl];
        uint4 v1 = By[(size_t)i1 * 8 + gl];
        uint4 v2 = By[(size_t)i2 * 8 + gl];
        uint4 v3 = By[(size_t)i3 * 8 + gl];
        uint4 v4 = By[(size_t)i4 * 8 + gl];
        uint4 v5 = By[(size_t)i5 * 8 + gl];
        uint4 v6 = By[(size_t)i6 * 8 + gl];
        uint4 v7 = By[(size_t)i7 * 8 + gl];
        acc8(acc, v0); acc8(acc, v1); acc8(acc, v2); acc8(acc, v3);
        acc8(acc, v4); acc8(acc, v5); acc8(acc, v6); acc8(acc, v7);
    }
    for (; p < e; ++p) acc8(acc, By[(size_t)csr[p] * 8 + gl]);
    float di = dinv[g];
    float4 ba = Bx[(size_t)g * 16 + gl * 2];
    float4 bb = Bx[(size_t)g * 16 + gl * 2 + 1];
    float4 oa, ob;
    oa.x = t2 * (ba.x - acc[0] * di); oa.y = t2 * (ba.y - acc[1] * di);
    oa.z = t2 * (ba.z - acc[2] * di); oa.w = t2 * (ba.w - acc[3] * di);
    ob.x = t2 * (bb.x - acc[4] * di); ob.y = t2 * (bb.y - acc[5] * di);
    ob.z = t2 * (bb.z - acc[6] * di); ob.w = t2 * (bb.w - acc[7] * di);
    hsel[(size_t)i * 16 + gl * 2] = oa;
    hsel[(size_t)i * 16 + gl * 2 + 1] = ob;
}

// ============ Final stage 1: vtmp = feat[node] + hsel[i]@W3 + b3 ; scores ============
// W3 read from global (L1 broadcast), LDS = sHt only.

__global__ __launch_bounds__(256) void final1_kernel(const float* __restrict__ feat,
        const float* __restrict__ hsel, const float* __restrict__ W3, const float* __restrict__ b3,
        const float* __restrict__ Wclf, const float* __restrict__ bclf,
        const int* __restrict__ nodes, float* __restrict__ vtmp, float* __restrict__ scores,
        int n) {
    __shared__ float sHt[64 * 68];       // 17KB padded
    __shared__ float sWclf[FEAT * 2];
    __shared__ float sbclf[2];
    __shared__ int sNodes[64];
    int tid = threadIdx.x;
    int base = blockIdx.x * 64;

    for (int i = tid; i < FEAT * 2; i += 256) sWclf[i] = Wclf[i];
    if (tid < 2) sbclf[tid] = bclf[tid];
    if (tid < 64) {
        int gi = base + tid;
        sNodes[tid] = (gi < n) ? nodes[gi] : 0;
    }
    __syncthreads();
    for (int it = 0; it < 16; ++it) {
        int id = it * 256 + tid;
        int r = id >> 6, c = id & 63;
        int gi = base + r;
        sHt[r * 68 + c] = (gi < n) ? hsel[(size_t)gi * EMB + c] : 0.0f;
    }
    __syncthreads();

    {
        int wv = tid >> 6, ln = tid & 63;
        float bc0 = sbclf[0], bc1 = sbclf[1];
        for (int q = 0; q < 16; ++q) {
            int r = wv * 16 + q;
            int nd = sNodes[r];
            float f0 = feat[(size_t)nd * FEAT + ln];
            float f1 = feat[(size_t)nd * FEAT + 64 + ln];
            float p0 = f0 * sWclf[ln * 2]     + f1 * sWclf[(64 + ln) * 2];
            float p1 = f0 * sWclf[ln * 2 + 1] + f1 * sWclf[(64 + ln) * 2 + 1];
            #pragma unroll
            for (int off = 32; off > 0; off >>= 1) {
                p0 += __shfl_xor(p0, off);
                p1 += __shfl_xor(p1, off);
            }
            int gi = base + r;
            if (ln == 0 && gi < n) {
                scores[(size_t)gi * 2]     = p0 + bc0;
                scores[(size_t)gi * 2 + 1] = p1 + bc1;
            }
        }
    }

    int tx = tid & 31, ty = tid >> 5;
    float acc[8][4];
    #pragma unroll
    for (int i = 0; i < 8; ++i)
        #pragma unroll
        for (int j = 0; j < 4; ++j) acc[i][j] = 0.0f;

    #pragma unroll 2
    for (int k4 = 0; k4 < EMB / 4; ++k4) {
        float4 a4[8];
        #pragma unroll
        for (int i = 0; i < 8; ++i)
            a4[i] = *(const float4*)&sHt[(ty * 8 + i) * 68 + k4 * 4];
        #pragma unroll
        for (int kk = 0; kk < 4; ++kk) {
            float4 bv = *(const float4*)&W3[(k4 * 4 + kk) * FEAT + tx * 4];
            #pragma unroll
            for (int i = 0; i < 8; ++i) {
                float a = ((const float*)&a4[i])[kk];
                acc[i][0] = fmaf(a, bv.x, acc[i][0]);
                acc[i][1] = fmaf(a, bv.y, acc[i][1]);
                acc[i][2] = fmaf(a, bv.z, acc[i][2]);
                acc[i][3] = fmaf(a, bv.w, acc[i][3]);
            }
        }
    }

    float4 b3v = *(const float4*)&b3[tx * 4];
    #pragma unroll
    for (int i = 0; i < 8; ++i) {
        int r = ty * 8 + i;
        int gi = base + r;
        int nd = sNodes[r];
        float4 fv = *(const float4*)&feat[(size_t)nd * FEAT + tx * 4];
        float4 o;
        o.x = acc[i][0] + b3v.x + fv.x;
        o.y = acc[i][1] + b3v.y + fv.y;
        o.z = acc[i][2] + b3v.z + fv.z;
        o.w = acc[i][3] + b3v.w + fv.w;
        if (gi < n) *(float4*)&vtmp[(size_t)gi * FEAT + tx * 4] = o;
    }
}

// ============ Final stage 2: out = relu(vtmp @ weight) ============
// weight read from global; LDS = sV only (32KB, swizzled).

__global__ __launch_bounds__(256) void final2_kernel(const float* __restrict__ vtmp,
        const float* __restrict__ weight, float* __restrict__ outc, int n) {
    __shared__ float sV[64 * FEAT];     // 32KB
    int tid = threadIdx.x;
    int base = blockIdx.x * 64;
    for (int i = tid; i < 64 * FEAT; i += 256) {
        int r = i >> 7, c = i & 127;
        int gi = base + r;
        int s = c >> 2;
        int idx = r * FEAT + (((s ^ ((r >> 2) & 7)) << 2) | (c & 3));
        sV[idx] = (gi < n) ? vtmp[(size_t)gi * FEAT + c] : 0.0f;
    }
    __syncthreads();

    int tx = tid & 15, ty = tid >> 4;
    float acc[4][4];
    #pragma unroll
    for (int i = 0; i < 4; ++i)
        #pragma unroll
        for (int j = 0; j < 4; ++j) acc[i][j] = 0.0f;

    #pragma unroll 4
    for (int k4 = 0; k4 < FEAT / 4; ++k4) {
        float4 a4[4];
        #pragma unroll
        for (int i = 0; i < 4; ++i) {
            int r = ty * 4 + i;
            a4[i] = *(const float4*)&sV[r * FEAT + ((k4 ^ (ty & 7)) << 2)];
        }
        #pragma unroll
        for (int kk = 0; kk < 4; ++kk) {
            float4 bv = *(const float4*)&weight[(k4 * 4 + kk) * EMB + tx * 4];
            #pragma unroll
            for (int i = 0; i < 4; ++i) {
                float a = ((const float*)&a4[i])[kk];
                acc[i][0] = fmaf(a, bv.x, acc[i][0]);
                acc[i][1] = fmaf(a, bv.y, acc[i][1]);
                acc[i][2] = fmaf(a, bv.z, acc[i][2]);
                acc[i][3] = fmaf(a, bv.w, acc[i][3]);
            }
        }
    }

    #pragma unroll
    for (int i = 0; i < 4; ++i) {
        int gi = base + ty * 4 + i;
        if (gi < n) {
            float4 o;
            o.x = fmaxf(acc[i][0], 0.0f); o.y = fmaxf(acc[i][1], 0.0f);
            o.z = fmaxf(acc[i][2], 0.0f); o.w = fmaxf(acc[i][3], 0.0f);
            *(float4*)&outc[(size_t)gi * EMB + tx * 4] = o;
        }
    }
}

// ============ launch ============

extern "C" void kernel_launch(void* const* d_in, const int* in_sizes, int n_in,
                              void* d_out, int out_size, void* d_ws, size_t ws_size,
                              hipStream_t stream) {
    const float* feat   = (const float*)d_in[0];
    const float* Wclf   = (const float*)d_in[1];
    const float* bclf   = (const float*)d_in[2];
    const float* W1     = (const float*)d_in[3];
    const float* b1     = (const float*)d_in[4];
    const float* W2     = (const float*)d_in[5];
    const float* b2     = (const float*)d_in[6];
    const float* W3     = (const float*)d_in[7];
    const float* b3     = (const float*)d_in[8];
    const float* weight = (const float*)d_in[9];
    const int* nodes    = (const int*)d_in[10];
    // d_in[11] = r1_neighs: DEAD (AGG_WEIGHT[0] == 0.0)
    const int* edge_src = (const int*)d_in[12];
    const int* edge_dst = (const int*)d_in[13];

    int n       = in_sizes[10];        // 8192
    int n_edges = in_sizes[12];        // 1600000
    int N       = in_sizes[0] / FEAT;  // 50000 (< 65536, required for u16 CSR)
    int nbuck   = (N + 255) >> 8;      // 196 (must be <= 256)
    int chunk   = (n_edges + NB - 1) / NB;

    char* ws = (char*)d_ws;
    size_t off = 0;
    auto alloc = [&](size_t bytes) -> void* {
        void* p = ws + off;
        off = (off + bytes + 255) & ~(size_t)255;
        return p;
    };
    int*      table  = (int*)     alloc((size_t)nbuck * NB * 4);
    int*      tscan  = (int*)     alloc((size_t)nbuck * NB * 4);
    int*      bsum   = (int*)     alloc(256 * 4);
    int*      boff   = (int*)     alloc(256 * 4);
    int*      rowptr = (int*)     alloc((size_t)(N + 1) * 4);
    float*    dinv   = (float*)   alloc((size_t)N * 4);
    unsigned* pairs  = (unsigned*)alloc((size_t)n_edges * 4);
    u16*      csr    = (u16*)     alloc((size_t)n_edges * 2);
    float*    Axf    = (float*)   alloc((size_t)N * EMB * 4);
    u16*      Ayf    = (u16*)     alloc((size_t)N * EMB * 2);
    float*    Bxf    = (float*)   alloc((size_t)N * EMB * 4);
    u16*      Byf    = (u16*)     alloc((size_t)N * EMB * 2);
    float*    hsel   = (float*)   alloc((size_t)n * EMB * 4);
    float*    vtmp   = (float*)   alloc((size_t)n * FEAT * 4);

    float* out_combined = (float*)d_out;                       // [n, 64]
    float* out_scores   = out_combined + (size_t)n * EMB;      // [n, 2]

    int L = nbuck * NB;   // 50176 table entries
    hist_kernel<<<NB, 256, 0, stream>>>(edge_dst, table, n_edges, nbuck, chunk);
    block_sum_kernel<<<nbuck, 256, 0, stream>>>(table, bsum, L);
    scan_bsum_kernel<<<1, 256, 0, stream>>>(bsum, boff, nbuck);
    scan_table_kernel<<<nbuck, 256, 0, stream>>>(table, boff, tscan, L);
    scatter_kernel<<<NB, 256, 0, stream>>>(edge_src, edge_dst, tscan, pairs, n_edges, nbuck, chunk);
    finalize_kernel<<<nbuck, 256, 0, stream>>>(pairs, boff, rowptr, dinv, csr, n_edges, N, nbuck);

    int mb = (N + 31) / 32;     // 1563 blocks
    mlp_kernel<<<mb, 256, 0, stream>>>(feat, W1, b1, W2, b2, dinv, Axf, Ayf, N);

    int lb = ((size_t)N * 8 + 255) / 256;
    // conv 0: theta = (3, -3, 0.75)
    lap_kernel<<<lb, 256, 0, stream>>>((const float4*)Axf, (const uint4*)Ayf,
                                       (float4*)Bxf, (uint4*)Byf, rowptr, csr, dinv, N);
    theta_kernel<<<lb, 256, 0, stream>>>((float4*)Axf, (uint4*)Ayf,
                                         (const float4*)Bxf, (const uint4*)Byf,
                                         rowptr, csr, dinv, N, 3.f, -3.f, 0.75f, 0);
    // conv 1: theta = (0, 3, -1.5)
    lap_kernel<<<lb, 256, 0, stream>>>((const float4*)Axf, (const uint4*)Ayf,
                                       (float4*)Bxf, (uint4*)Byf, rowptr, csr, dinv, N);
    theta_kernel<<<lb, 256, 0, stream>>>((float4*)Axf, (uint4*)Ayf,
                                         (const float4*)Bxf, (const uint4*)Byf,
                                         rowptr, csr, dinv, N, 0.f, 3.f, -1.5f, 1);
    // conv 2: theta = (0, 0, 0.75) -> only needed at `nodes`
    lap_kernel<<<lb, 256, 0, stream>>>((const float4*)Axf, (const uint4*)Ayf,
                                       (float4*)Bxf, (uint4*)Byf, rowptr, csr, dinv, N);
    int selb = ((size_t)n * 8 + 255) / 256;
    theta_sel_kernel<<<selb, 256, 0, stream>>>((const float4*)Bxf, (const uint4*)Byf,
                                               rowptr, csr, dinv, nodes,
                                               (float4*)hsel, n, 0.75f);

    int fb = (n + 63) / 64;
    final1_kernel<<<fb, 256, 0, stream>>>(feat, hsel, W3, b3, Wclf, bclf, nodes,
                                          vtmp, out_scores, n);
    final2_kernel<<<fb, 256, 0, stream>>>(vtmp, weight, out_combined, n);
}

// Round 15
// 342.349 us; speedup vs baseline: 1.1184x; 1.1017x over previous
//
#include <hip/hip_runtime.h>

#define FEAT 128
#define EMB 64
#define NB 256          // blocks for edge chunking (hist/scatter)

typedef unsigned short u16;
typedef __attribute__((ext_vector_type(8))) short bf16x8;
typedef __attribute__((ext_vector_type(4))) float f32x4;

__device__ inline u16 f2bf(float f) {
    unsigned u = __float_as_uint(f);
    unsigned r = (u + 0x7FFFu + ((u >> 16) & 1u)) >> 16;
    return (u16)r;
}
__device__ inline unsigned pack2(float lo, float hi) {
    return ((unsigned)f2bf(hi) << 16) | (unsigned)f2bf(lo);
}
__device__ inline void acc8(float* acc, uint4 v) {
    acc[0] += __uint_as_float(v.x << 16);
    acc[1] += __uint_as_float(v.x & 0xFFFF0000u);
    acc[2] += __uint_as_float(v.y << 16);
    acc[3] += __uint_as_float(v.y & 0xFFFF0000u);
    acc[4] += __uint_as_float(v.z << 16);
    acc[5] += __uint_as_float(v.z & 0xFFFF0000u);
    acc[6] += __uint_as_float(v.w << 16);
    acc[7] += __uint_as_float(v.w & 0xFFFF0000u);
}

// ============ CSR build: 2-level counting sort, LDS atomics only ============

__global__ __launch_bounds__(256) void hist_kernel(const int* __restrict__ edge_dst,
        int* __restrict__ table, int n_edges, int nbuck, int chunk) {
    __shared__ int hist[256];
    int t = threadIdx.x, b = blockIdx.x;
    hist[t] = 0;
    __syncthreads();
    int start = b * chunk, end = min(start + chunk, n_edges);
    for (int e = start + t; e < end; e += 256) {
        int d = __builtin_nontemporal_load(&edge_dst[e]);
        atomicAdd(&hist[d >> 8], 1);
    }
    __syncthreads();
    if (t < nbuck) table[t * NB + b] = hist[t];
}

__global__ void block_sum_kernel(const int* __restrict__ v, int* __restrict__ bsum, int n) {
    __shared__ int sd[256];
    int t = threadIdx.x;
    int i = blockIdx.x * 256 + t;
    sd[t] = (i < n) ? v[i] : 0;
    __syncthreads();
    for (int off = 128; off > 0; off >>= 1) {
        if (t < off) sd[t] += sd[t + off];
        __syncthreads();
    }
    if (t == 0) bsum[blockIdx.x] = sd[0];
}

__global__ void scan_bsum_kernel(const int* __restrict__ bsum, int* __restrict__ boff, int nb) {
    __shared__ int sd[256];
    int t = threadIdx.x;
    int v = (t < nb) ? bsum[t] : 0;
    sd[t] = v;
    __syncthreads();
    for (int off = 1; off < 256; off <<= 1) {
        int u = (t >= off) ? sd[t - off] : 0;
        __syncthreads();
        sd[t] += u;
        __syncthreads();
    }
    if (t < nb) boff[t] = sd[t] - v;
}

__global__ void scan_table_kernel(const int* __restrict__ tin, const int* __restrict__ boff,
                                  int* __restrict__ tout, int n) {
    __shared__ int sd[256];
    int t = threadIdx.x;
    int i = blockIdx.x * 256 + t;
    int v = (i < n) ? tin[i] : 0;
    sd[t] = v;
    __syncthreads();
    for (int off = 1; off < 256; off <<= 1) {
        int u = (t >= off) ? sd[t - off] : 0;
        __syncthreads();
        sd[t] += u;
        __syncthreads();
    }
    if (i < n) tout[i] = boff[blockIdx.x] + sd[t] - v;
}

__global__ __launch_bounds__(256) void scatter_kernel(
        const int* __restrict__ edge_src, const int* __restrict__ edge_dst,
        const int* __restrict__ tscan, unsigned* __restrict__ pairs,
        int n_edges, int nbuck, int chunk) {
    __shared__ int cur[256];
    int t = threadIdx.x, b = blockIdx.x;
    if (t < nbuck) cur[t] = tscan[t * NB + b];
    __syncthreads();
    int start = b * chunk, end = min(start + chunk, n_edges);
    for (int e = start + t; e < end; e += 256) {
        int d = __builtin_nontemporal_load(&edge_dst[e]);
        int s = __builtin_nontemporal_load(&edge_src[e]);
        int pos = atomicAdd(&cur[d >> 8], 1);
        pairs[pos] = ((unsigned)(d & 255) << 16) | (unsigned)s;
    }
}

__global__ __launch_bounds__(256) void finalize_kernel(
        const unsigned* __restrict__ pairs, const int* __restrict__ boff,
        int* __restrict__ rowptr, float* __restrict__ dinv, u16* __restrict__ csr,
        int n_edges, int N, int nbuck) {
    __shared__ int hist[256];
    __shared__ int scan[256];
    __shared__ int cur[256];
    int b = blockIdx.x, t = threadIdx.x;
    int node0 = b << 8;
    int base = boff[b];
    int end  = (b + 1 < nbuck) ? boff[b + 1] : n_edges;
    hist[t] = 0;
    __syncthreads();
    for (int p = base + t; p < end; p += 256)
        atomicAdd(&hist[pairs[p] >> 16], 1);
    __syncthreads();
    int v = hist[t];
    scan[t] = v;
    __syncthreads();
    for (int off = 1; off < 256; off <<= 1) {
        int u = (t >= off) ? scan[t - off] : 0;
        __syncthreads();
        scan[t] += u;
        __syncthreads();
    }
    int excl = scan[t] - v;
    cur[t] = base + excl;
    int node = node0 + t;
    if (node < N) {
        rowptr[node] = base + excl;
        dinv[node] = rsqrtf(fmaxf((float)v, 1.0f));
    }
    if (b == 0 && t == 0) rowptr[N] = n_edges;
    __syncthreads();
    for (int p = base + t; p < end; p += 256) {
        unsigned pr = pairs[p];
        int pos = atomicAdd(&cur[pr >> 16], 1);
        csr[pos] = (u16)(pr & 0xFFFFu);
    }
}

// ============ Weight prep: transpose W1/W2 into B-fragment layout, bf16 ============
// Wt[kb][c][j] = bf16(W[(kb*8+j)*EMB + c])  -> lane's 8-elem b-frag is 16B contiguous.

__global__ __launch_bounds__(256) void wprep_kernel(const float* __restrict__ W1,
        const float* __restrict__ W2, u16* __restrict__ W1t, u16* __restrict__ W2t) {
    int t = blockIdx.x * 256 + threadIdx.x;
    if (t < 16 * 64 * 8) {
        int j = t & 7, c = (t >> 3) & 63, kb = t >> 9;
        W1t[t] = f2bf(W1[(kb * 8 + j) * EMB + c]);
    }
    if (t < 8 * 64 * 8) {
        int j = t & 7, c = (t >> 3) & 63, kb = t >> 9;
        W2t[t] = f2bf(W2[(kb * 8 + j) * EMB + c]);
    }
}

// ============ MLP via MFMA: A = relu(relu(feat@W1+b1)@W2+b2); Ay = bf16(A*dinv) ============
// 4 waves/block, each wave owns 16 rows. mfma_f32_16x16x32_bf16.
// A-frag: lane l holds A[l&15][(l>>4)*8+j]; B-frag: B[(l>>4)*8+j][l&15];
// C/D: col=lane&15, row=(lane>>4)*4+reg (m89-verified mapping).

__global__ __launch_bounds__(256) void mlp_kernel(const float* __restrict__ feat,
        const u16* __restrict__ W1t, const float* __restrict__ b1,
        const u16* __restrict__ W2t, const float* __restrict__ b2,
        const float* __restrict__ dinv,
        float* __restrict__ A, u16* __restrict__ Ay, int n) {
    __shared__ u16 sH[4][16 * 72];   // per-wave h tile, padded stride 72 (2-way alias = free)
    int tid = threadIdx.x;
    int w = tid >> 6, l = tid & 63;
    int lo = l & 15, hi = l >> 4;
    int row0 = blockIdx.x * 64 + w * 16;

    // A-frags for GEMM1 (K=128 = 4 x 32); coalesced: 4 lanes of same row cover 128B
    bf16x8 afr[4];
    int arow = min(row0 + lo, n - 1);
    const float* fbase = feat + (size_t)arow * FEAT + hi * 8;
    #pragma unroll
    for (int ks = 0; ks < 4; ++ks) {
        float4 p0 = *(const float4*)(fbase + ks * 32);
        float4 p1 = *(const float4*)(fbase + ks * 32 + 4);
        bf16x8 a;
        a[0] = (short)f2bf(p0.x); a[1] = (short)f2bf(p0.y);
        a[2] = (short)f2bf(p0.z); a[3] = (short)f2bf(p0.w);
        a[4] = (short)f2bf(p1.x); a[5] = (short)f2bf(p1.y);
        a[6] = (short)f2bf(p1.z); a[7] = (short)f2bf(p1.w);
        afr[ks] = a;
    }

    // GEMM1: h[16][64] = relu(feat_tile @ W1 + b1), 4 col-tiles of 16
    #pragma unroll
    for (int ct = 0; ct < 4; ++ct) {
        f32x4 acc = {0.f, 0.f, 0.f, 0.f};
        #pragma unroll
        for (int ks = 0; ks < 4; ++ks) {
            bf16x8 b = *(const bf16x8*)&W1t[((ks * 4 + hi) * 64 + ct * 16 + lo) * 8];
            acc = __builtin_amdgcn_mfma_f32_16x16x32_bf16(afr[ks], b, acc, 0, 0, 0);
        }
        int col = ct * 16 + lo;
        float bias = b1[col];
        #pragma unroll
        for (int r = 0; r < 4; ++r) {
            float h = fmaxf(acc[r] + bias, 0.f);
            sH[w][(hi * 4 + r) * 72 + col] = f2bf(h);
        }
    }
    __syncthreads();

    // GEMM2 A-frags from LDS (K=64 = 2 x 32)
    bf16x8 a2[2];
    #pragma unroll
    for (int ks = 0; ks < 2; ++ks)
        a2[ks] = *(const bf16x8*)&sH[w][lo * 72 + ks * 32 + hi * 8];

    float dv[4];
    #pragma unroll
    for (int r = 0; r < 4; ++r)
        dv[r] = dinv[min(row0 + hi * 4 + r, n - 1)];

    #pragma unroll
    for (int ct = 0; ct < 4; ++ct) {
        f32x4 acc = {0.f, 0.f, 0.f, 0.f};
        #pragma unroll
        for (int ks = 0; ks < 2; ++ks) {
            bf16x8 b = *(const bf16x8*)&W2t[((ks * 4 + hi) * 64 + ct * 16 + lo) * 8];
            acc = __builtin_amdgcn_mfma_f32_16x16x32_bf16(a2[ks], b, acc, 0, 0, 0);
        }
        int col = ct * 16 + lo;
        float bias = b2[col];
        #pragma unroll
        for (int r = 0; r < 4; ++r) {
            int grow = row0 + hi * 4 + r;
            if (grow < n) {
                float o = fmaxf(acc[r] + bias, 0.f);
                A[(size_t)grow * EMB + col] = o;
                Ay[(size_t)grow * EMB + col] = f2bf(o * dv[r]);
            }
        }
    }
}

// ============ Laplacian kernels ============
// y = bf16(x*dinv) packed 2/uint. 8 lanes/node, uint4 per lane, unroll x8.

__global__ __launch_bounds__(256) void lap_kernel(
        const float4* __restrict__ x, const uint4* __restrict__ y,
        float4* __restrict__ Bx, uint4* __restrict__ By,
        const int* __restrict__ rowptr, const u16* __restrict__ csr,
        const float* __restrict__ dinv, int n) {
    int tid = blockIdx.x * blockDim.x + threadIdx.x;
    int g = tid >> 3, gl = tid & 7;
    if (g >= n) return;
    int s = rowptr[g], e = rowptr[g + 1];
    float acc[8] = {0.f,0.f,0.f,0.f,0.f,0.f,0.f,0.f};
    int p = s;
    for (; p + 7 < e; p += 8) {
        int i0 = csr[p],   i1 = csr[p+1], i2 = csr[p+2], i3 = csr[p+3];
        int i4 = csr[p+4], i5 = csr[p+5], i6 = csr[p+6], i7 = csr[p+7];
        uint4 v0 = y[(size_t)i0 * 8 + gl];
        uint4 v1 = y[(size_t)i1 * 8 + gl];
        uint4 v2 = y[(size_t)i2 * 8 + gl];
        uint4 v3 = y[(size_t)i3 * 8 + gl];
        uint4 v4 = y[(size_t)i4 * 8 + gl];
        uint4 v5 = y[(size_t)i5 * 8 + gl];
        uint4 v6 = y[(size_t)i6 * 8 + gl];
        uint4 v7 = y[(size_t)i7 * 8 + gl];
        acc8(acc, v0); acc8(acc, v1); acc8(acc, v2); acc8(acc, v3);
        acc8(acc, v4); acc8(acc, v5); acc8(acc, v6); acc8(acc, v7);
    }
    for (; p < e; ++p) {
        int i0 = csr[p];
        acc8(acc, y[(size_t)i0 * 8 + gl]);
    }
    float di = dinv[g];
    float4 xa = x[(size_t)g * 16 + gl * 2];
    float4 xb = x[(size_t)g * 16 + gl * 2 + 1];
    float4 oa, ob;
    oa.x = xa.x - acc[0] * di; oa.y = xa.y - acc[1] * di;
    oa.z = xa.z - acc[2] * di; oa.w = xa.w - acc[3] * di;
    ob.x = xb.x - acc[4] * di; ob.y = xb.y - acc[5] * di;
    ob.z = xb.z - acc[6] * di; ob.w = xb.w - acc[7] * di;
    Bx[(size_t)g * 16 + gl * 2] = oa;
    Bx[(size_t)g * 16 + gl * 2 + 1] = ob;
    uint4 oy;
    oy.x = pack2(oa.x * di, oa.y * di);
    oy.y = pack2(oa.z * di, oa.w * di);
    oy.z = pack2(ob.x * di, ob.y * di);
    oy.w = pack2(ob.z * di, ob.w * di);
    By[(size_t)g * 8 + gl] = oy;
}

__global__ __launch_bounds__(256) void theta_kernel(
        float4* __restrict__ Ax, uint4* __restrict__ Ay,
        const float4* __restrict__ Bx, const uint4* __restrict__ By,
        const int* __restrict__ rowptr, const u16* __restrict__ csr,
        const float* __restrict__ dinv, int n, float t0, float t1, float t2, int skip_a) {
    int tid = blockIdx.x * blockDim.x + threadIdx.x;
    int g = tid >> 3, gl = tid & 7;
    if (g >= n) return;
    int s = rowptr[g], e = rowptr[g + 1];
    float acc[8] = {0.f,0.f,0.f,0.f,0.f,0.f,0.f,0.f};
    int p = s;
    for (; p + 7 < e; p += 8) {
        int i0 = csr[p],   i1 = csr[p+1], i2 = csr[p+2], i3 = csr[p+3];
        int i4 = csr[p+4], i5 = csr[p+5], i6 = csr[p+6], i7 = csr[p+7];
        uint4 v0 = By[(size_t)i0 * 8 + gl];
        uint4 v1 = By[(size_t)i1 * 8 + gl];
        uint4 v2 = By[(size_t)i2 * 8 + gl];
        uint4 v3 = By[(size_t)i3 * 8 + gl];
        uint4 v4 = By[(size_t)i4 * 8 + gl];
        uint4 v5 = By[(size_t)i5 * 8 + gl];
        uint4 v6 = By[(size_t)i6 * 8 + gl];
        uint4 v7 = By[(size_t)i7 * 8 + gl];
        acc8(acc, v0); acc8(acc, v1); acc8(acc, v2); acc8(acc, v3);
        acc8(acc, v4); acc8(acc, v5); acc8(acc, v6); acc8(acc, v7);
    }
    for (; p < e; ++p) {
        int i0 = csr[p];
        acc8(acc, By[(size_t)i0 * 8 + gl]);
    }
    float di = dinv[g];
    float4 ba = Bx[(size_t)g * 16 + gl * 2];
    float4 bb = Bx[(size_t)g * 16 + gl * 2 + 1];
    float4 aa = {0.f,0.f,0.f,0.f}, ab = {0.f,0.f,0.f,0.f};
    if (!skip_a) {
        aa = Ax[(size_t)g * 16 + gl * 2];
        ab = Ax[(size_t)g * 16 + gl * 2 + 1];
    }
    float4 oa, ob;
    oa.x = t0 * aa.x + t1 * ba.x + t2 * (ba.x - acc[0] * di);
    oa.y = t0 * aa.y + t1 * ba.y + t2 * (ba.y - acc[1] * di);
    oa.z = t0 * aa.z + t1 * ba.z + t2 * (ba.z - acc[2] * di);
    oa.w = t0 * aa.w + t1 * ba.w + t2 * (ba.w - acc[3] * di);
    ob.x = t0 * ab.x + t1 * bb.x + t2 * (bb.x - acc[4] * di);
    ob.y = t0 * ab.y + t1 * bb.y + t2 * (bb.y - acc[5] * di);
    ob.z = t0 * ab.z + t1 * bb.z + t2 * (bb.z - acc[6] * di);
    ob.w = t0 * ab.w + t1 * bb.w + t2 * (bb.w - acc[7] * di);
    Ax[(size_t)g * 16 + gl * 2] = oa;
    Ax[(size_t)g * 16 + gl * 2 + 1] = ob;
    uint4 oy;
    oy.x = pack2(oa.x * di, oa.y * di);
    oy.y = pack2(oa.z * di, oa.w * di);
    oy.z = pack2(ob.x * di, ob.y * di);
    oy.w = pack2(ob.z * di, ob.w * di);
    Ay[(size_t)g * 8 + gl] = oy;
}

__global__ __launch_bounds__(256) void theta_sel_kernel(
        const float4* __restrict__ Bx, const uint4* __restrict__ By,
        const int* __restrict__ rowptr, const u16* __restrict__ csr,
        const float* __restrict__ dinv, const int* __restrict__ nodes,
        float4* __restrict__ hsel, int n, float t2) {
    int tid = blockIdx.x * blockDim.x + threadIdx.x;
    int i = tid >> 3, gl = tid & 7;
    if (i >= n) return;
    int g = nodes[i];
    int s = rowptr[g], e = rowptr[g + 1];
    float acc[8] = {0.f,0.f,0.f,0.f,0.f,0.f,0.f,0.f};
    int p = s;
    for (; p + 7 < e; p += 8) {
        int i0 = csr[p],   i1 = csr[p+1], i2 = csr[p+2], i3 = csr[p+3];
        int i4 = csr[p+4], i5 = csr[p+5], i6 = csr[p+6], i7 = csr[p+7];
        uint4 v0 = By[(size_t)i0 * 8 + gl];
        uint4 v1 = By[(size_t)i1 * 8 + gl];
        uint4 v2 = By[(size_t)i2 * 8 + gl];
        uint4 v3 = By[(size_t)i3 * 8 + gl];
        uint4 v4 = By[(size_t)i4 * 8 + gl];
        uint4 v5 = By[(size_t)i5 * 8 + gl];
        uint4 v6 = By[(size_t)i6 * 8 + gl];
        uint4 v7 = By[(size_t)i7 * 8 + gl];
        acc8(acc, v0); acc8(acc, v1); acc8(acc, v2); acc8(acc, v3);
        acc8(acc, v4); acc8(acc, v5); acc8(acc, v6); acc8(acc, v7);
    }
    for (; p < e; ++p) acc8(acc, By[(size_t)csr[p] * 8 + gl]);
    float di = dinv[g];
    float4 ba = Bx[(size_t)g * 16 + gl * 2];
    float4 bb = Bx[(size_t)g * 16 + gl * 2 + 1];
    float4 oa, ob;
    oa.x = t2 * (ba.x - acc[0] * di); oa.y = t2 * (ba.y - acc[1] * di);
    oa.z = t2 * (ba.z - acc[2] * di); oa.w = t2 * (ba.w - acc[3] * di);
    ob.x = t2 * (bb.x - acc[4] * di); ob.y = t2 * (bb.y - acc[5] * di);
    ob.z = t2 * (bb.z - acc[6] * di); ob.w = t2 * (bb.w - acc[7] * di);
    hsel[(size_t)i * 16 + gl * 2] = oa;
    hsel[(size_t)i * 16 + gl * 2 + 1] = ob;
}

// ============ Final stage 1: vtmp = feat[node] + hsel[i]@W3 + b3 ; scores ============

__global__ __launch_bounds__(256) void final1_kernel(const float* __restrict__ feat,
        const float* __restrict__ hsel, const float* __restrict__ W3, const float* __restrict__ b3,
        const float* __restrict__ Wclf, const float* __restrict__ bclf,
        const int* __restrict__ nodes, float* __restrict__ vtmp, float* __restrict__ scores,
        int n) {
    __shared__ float sHt[64 * 68];       // 17KB padded
    __shared__ float sWclf[FEAT * 2];
    __shared__ float sbclf[2];
    __shared__ int sNodes[64];
    int tid = threadIdx.x;
    int base = blockIdx.x * 64;

    for (int i = tid; i < FEAT * 2; i += 256) sWclf[i] = Wclf[i];
    if (tid < 2) sbclf[tid] = bclf[tid];
    if (tid < 64) {
        int gi = base + tid;
        sNodes[tid] = (gi < n) ? nodes[gi] : 0;
    }
    __syncthreads();
    for (int it = 0; it < 16; ++it) {
        int id = it * 256 + tid;
        int r = id >> 6, c = id & 63;
        int gi = base + r;
        sHt[r * 68 + c] = (gi < n) ? hsel[(size_t)gi * EMB + c] : 0.0f;
    }
    __syncthreads();

    {
        int wv = tid >> 6, ln = tid & 63;
        float bc0 = sbclf[0], bc1 = sbclf[1];
        for (int q = 0; q < 16; ++q) {
            int r = wv * 16 + q;
            int nd = sNodes[r];
            float f0 = feat[(size_t)nd * FEAT + ln];
            float f1 = feat[(size_t)nd * FEAT + 64 + ln];
            float p0 = f0 * sWclf[ln * 2]     + f1 * sWclf[(64 + ln) * 2];
            float p1 = f0 * sWclf[ln * 2 + 1] + f1 * sWclf[(64 + ln) * 2 + 1];
            #pragma unroll
            for (int off = 32; off > 0; off >>= 1) {
                p0 += __shfl_xor(p0, off);
                p1 += __shfl_xor(p1, off);
            }
            int gi = base + r;
            if (ln == 0 && gi < n) {
                scores[(size_t)gi * 2]     = p0 + bc0;
                scores[(size_t)gi * 2 + 1] = p1 + bc1;
            }
        }
    }

    int tx = tid & 31, ty = tid >> 5;
    float acc[8][4];
    #pragma unroll
    for (int i = 0; i < 8; ++i)
        #pragma unroll
        for (int j = 0; j < 4; ++j) acc[i][j] = 0.0f;

    #pragma unroll 2
    for (int k4 = 0; k4 < EMB / 4; ++k4) {
        float4 a4[8];
        #pragma unroll
        for (int i = 0; i < 8; ++i)
            a4[i] = *(const float4*)&sHt[(ty * 8 + i) * 68 + k4 * 4];
        #pragma unroll
        for (int kk = 0; kk < 4; ++kk) {
            float4 bv = *(const float4*)&W3[(k4 * 4 + kk) * FEAT + tx * 4];
            #pragma unroll
            for (int i = 0; i < 8; ++i) {
                float a = ((const float*)&a4[i])[kk];
                acc[i][0] = fmaf(a, bv.x, acc[i][0]);
                acc[i][1] = fmaf(a, bv.y, acc[i][1]);
                acc[i][2] = fmaf(a, bv.z, acc[i][2]);
                acc[i][3] = fmaf(a, bv.w, acc[i][3]);
            }
        }
    }

    float4 b3v = *(const float4*)&b3[tx * 4];
    #pragma unroll
    for (int i = 0; i < 8; ++i) {
        int r = ty * 8 + i;
        int gi = base + r;
        int nd = sNodes[r];
        float4 fv = *(const float4*)&feat[(size_t)nd * FEAT + tx * 4];
        float4 o;
        o.x = acc[i][0] + b3v.x + fv.x;
        o.y = acc[i][1] + b3v.y + fv.y;
        o.z = acc[i][2] + b3v.z + fv.z;
        o.w = acc[i][3] + b3v.w + fv.w;
        if (gi < n) *(float4*)&vtmp[(size_t)gi * FEAT + tx * 4] = o;
    }
}

// ============ Final stage 2: out = relu(vtmp @ weight) ============

__global__ __launch_bounds__(256) void final2_kernel(const float* __restrict__ vtmp,
        const float* __restrict__ weight, float* __restrict__ outc, int n) {
    __shared__ float sV[64 * FEAT];     // 32KB
    int tid = threadIdx.x;
    int base = blockIdx.x * 64;
    for (int i = tid; i < 64 * FEAT; i += 256) {
        int r = i >> 7, c = i & 127;
        int gi = base + r;
        int s = c >> 2;
        int idx = r * FEAT + (((s ^ ((r >> 2) & 7)) << 2) | (c & 3));
        sV[idx] = (gi < n) ? vtmp[(size_t)gi * FEAT + c] : 0.0f;
    }
    __syncthreads();

    int tx = tid & 15, ty = tid >> 4;
    float acc[4][4];
    #pragma unroll
    for (int i = 0; i < 4; ++i)
        #pragma unroll
        for (int j = 0; j < 4; ++j) acc[i][j] = 0.0f;

    #pragma unroll 4
    for (int k4 = 0; k4 < FEAT / 4; ++k4) {
        float4 a4[4];
        #pragma unroll
        for (int i = 0; i < 4; ++i) {
            int r = ty * 4 + i;
            a4[i] = *(const float4*)&sV[r * FEAT + ((k4 ^ (ty & 7)) << 2)];
        }
        #pragma unroll
        for (int kk = 0; kk < 4; ++kk) {
            float4 bv = *(const float4*)&weight[(k4 * 4 + kk) * EMB + tx * 4];
            #pragma unroll
            for (int i = 0; i < 4; ++i) {
                float a = ((const float*)&a4[i])[kk];
                acc[i][0] = fmaf(a, bv.x, acc[i][0]);
                acc[i][1] = fmaf(a, bv.y, acc[i][1]);
                acc[i][2] = fmaf(a, bv.z, acc[i][2]);
                acc[i][3] = fmaf(a, bv.w, acc[i][3]);
            }
        }
    }

    #pragma unroll
    for (int i = 0; i < 4; ++i) {
        int gi = base + ty * 4 + i;
        if (gi < n) {
            float4 o;
            o.x = fmaxf(acc[i][0], 0.0f); o.y = fmaxf(acc[i][1], 0.0f);
            o.z = fmaxf(acc[i][2], 0.0f); o.w = fmaxf(acc[i][3], 0.0f);
            *(float4*)&outc[(size_t)gi * EMB + tx * 4] = o;
        }
    }
}

// ============ launch ============

extern "C" void kernel_launch(void* const* d_in, const int* in_sizes, int n_in,
                              void* d_out, int out_size, void* d_ws, size_t ws_size,
                              hipStream_t stream) {
    const float* feat   = (const float*)d_in[0];
    const float* Wclf   = (const float*)d_in[1];
    const float* bclf   = (const float*)d_in[2];
    const float* W1     = (const float*)d_in[3];
    const float* b1     = (const float*)d_in[4];
    const float* W2     = (const float*)d_in[5];
    const float* b2     = (const float*)d_in[6];
    const float* W3     = (const float*)d_in[7];
    const float* b3     = (const float*)d_in[8];
    const float* weight = (const float*)d_in[9];
    const int* nodes    = (const int*)d_in[10];
    // d_in[11] = r1_neighs: DEAD (AGG_WEIGHT[0] == 0.0)
    const int* edge_src = (const int*)d_in[12];
    const int* edge_dst = (const int*)d_in[13];

    int n       = in_sizes[10];        // 8192
    int n_edges = in_sizes[12];        // 1600000
    int N       = in_sizes[0] / FEAT;  // 50000 (< 65536, required for u16 CSR)
    int nbuck   = (N + 255) >> 8;      // 196 (must be <= 256)
    int chunk   = (n_edges + NB - 1) / NB;

    char* ws = (char*)d_ws;
    size_t off = 0;
    auto alloc = [&](size_t bytes) -> void* {
        void* p = ws + off;
        off = (off + bytes + 255) & ~(size_t)255;
        return p;
    };
    int*      table  = (int*)     alloc((size_t)nbuck * NB * 4);
    int*      tscan  = (int*)     alloc((size_t)nbuck * NB * 4);
    int*      bsum   = (int*)     alloc(256 * 4);
    int*      boff   = (int*)     alloc(256 * 4);
    int*      rowptr = (int*)     alloc((size_t)(N + 1) * 4);
    float*    dinv   = (float*)   alloc((size_t)N * 4);
    unsigned* pairs  = (unsigned*)alloc((size_t)n_edges * 4);
    u16*      csr    = (u16*)     alloc((size_t)n_edges * 2);
    u16*      W1t    = (u16*)     alloc(16 * 64 * 8 * 2);
    u16*      W2t    = (u16*)     alloc(8 * 64 * 8 * 2);
    float*    Axf    = (float*)   alloc((size_t)N * EMB * 4);
    u16*      Ayf    = (u16*)     alloc((size_t)N * EMB * 2);
    float*    Bxf    = (float*)   alloc((size_t)N * EMB * 4);
    u16*      Byf    = (u16*)     alloc((size_t)N * EMB * 2);
    float*    hsel   = (float*)   alloc((size_t)n * EMB * 4);
    float*    vtmp   = (float*)   alloc((size_t)n * FEAT * 4);

    float* out_combined = (float*)d_out;                       // [n, 64]
    float* out_scores   = out_combined + (size_t)n * EMB;      // [n, 2]

    int L = nbuck * NB;   // 50176 table entries
    wprep_kernel<<<32, 256, 0, stream>>>(W1, W2, W1t, W2t);
    hist_kernel<<<NB, 256, 0, stream>>>(edge_dst, table, n_edges, nbuck, chunk);
    block_sum_kernel<<<nbuck, 256, 0, stream>>>(table, bsum, L);
    scan_bsum_kernel<<<1, 256, 0, stream>>>(bsum, boff, nbuck);
    scan_table_kernel<<<nbuck, 256, 0, stream>>>(table, boff, tscan, L);
    scatter_kernel<<<NB, 256, 0, stream>>>(edge_src, edge_dst, tscan, pairs, n_edges, nbuck, chunk);
    finalize_kernel<<<nbuck, 256, 0, stream>>>(pairs, boff, rowptr, dinv, csr, n_edges, N, nbuck);

    int mb = (N + 63) / 64;     // 782
    mlp_kernel<<<mb, 256, 0, stream>>>(feat, W1t, b1, W2t, b2, dinv, Axf, Ayf, N);

    int lb = ((size_t)N * 8 + 255) / 256;
    // conv 0: theta = (3, -3, 0.75)
    lap_kernel<<<lb, 256, 0, stream>>>((const float4*)Axf, (const uint4*)Ayf,
                                       (float4*)Bxf, (uint4*)Byf, rowptr, csr, dinv, N);
    theta_kernel<<<lb, 256, 0, stream>>>((float4*)Axf, (uint4*)Ayf,
                                         (const float4*)Bxf, (const uint4*)Byf,
                                         rowptr, csr, dinv, N, 3.f, -3.f, 0.75f, 0);
    // conv 1: theta = (0, 3, -1.5)
    lap_kernel<<<lb, 256, 0, stream>>>((const float4*)Axf, (const uint4*)Ayf,
                                       (float4*)Bxf, (uint4*)Byf, rowptr, csr, dinv, N);
    theta_kernel<<<lb, 256, 0, stream>>>((float4*)Axf, (uint4*)Ayf,
                                         (const float4*)Bxf, (const uint4*)Byf,
                                         rowptr, csr, dinv, N, 0.f, 3.f, -1.5f, 1);
    // conv 2: theta = (0, 0, 0.75) -> only needed at `nodes`
    lap_kernel<<<lb, 256, 0, stream>>>((const float4*)Axf, (const uint4*)Ayf,
                                       (float4*)Bxf, (uint4*)Byf, rowptr, csr, dinv, N);
    int selb = ((size_t)n * 8 + 255) / 256;
    theta_sel_kernel<<<selb, 256, 0, stream>>>((const float4*)Bxf, (const uint4*)Byf,
                                               rowptr, csr, dinv, nodes,
                                               (float4*)hsel, n, 0.75f);

    int fb = (n + 63) / 64;
    final1_kernel<<<fb, 256, 0, stream>>>(feat, hsel, W3, b3, Wclf, bclf, nodes,
                                          vtmp, out_scores, n);
    final2_kernel<<<fb, 256, 0, stream>>>(vtmp, weight, out_combined, n);
}